// Round 14
// baseline (632.173 us; speedup 1.0000x reference)
//
#include <hip/hip_runtime.h>

// SpatialHRVQTokenizer: 3-level VQ forward.
// Main GEMM: single-term f16 MFMA (hi*hi), B global->register (no K-loop barriers,
// r13-proven race-free). Rows with approx top-2 gap < RTAU=0.5 re-solved in fp64.
// q-gather split into its own streaming kernel (r13: write tail kept main at 2 TB/s).
// Output (flat fp32): idx0[0,32768) idx1[...,163840) idx2[...,294912)
//   loss[294912]  q0[294913..)  q1[12877825..)  q2[63209473..)

typedef _Float16 half8 __attribute__((ext_vector_type(8)));
typedef float f32x16 __attribute__((ext_vector_type(16)));

#define D_MODEL 384
#define NSEG 96
#define NKT 12
#define BM 64
#define RTAU 0.5f

__device__ __forceinline__ float4 ld4(const float* p) { return *(const float4*)p; }

__device__ __forceinline__ half8 cvt8h(const float4& a, const float4& b) {
  half8 h;
  h[0] = (_Float16)a.x; h[1] = (_Float16)a.y; h[2] = (_Float16)a.z; h[3] = (_Float16)a.w;
  h[4] = (_Float16)b.x; h[5] = (_Float16)b.y; h[6] = (_Float16)b.z; h[7] = (_Float16)b.w;
  return h;
}

// ---------------- code norms + counter zeroing ----------------
__global__ __launch_bounds__(64) void vq_norms(const float* __restrict__ c0,
                                               const float* __restrict__ c1,
                                               const float* __restrict__ c2,
                                               float* __restrict__ en,
                                               int* __restrict__ counts) {
  if (blockIdx.x == 0 && threadIdx.x < 4) counts[threadIdx.x] = 0;
  const int row = blockIdx.x;  // 0..767
  const float* cb = (row < 256) ? c0 : ((row < 512) ? c1 : c2);
  const int n = row & 255;
  const int lane = threadIdx.x;
  const float* r = cb + (size_t)n * D_MODEL;
  float s = 0.f;
  for (int c = lane; c < D_MODEL; c += 64) s = fmaf(r[c], r[c], s);
  for (int m = 1; m < 64; m <<= 1) s += __shfl_xor(s, m, 64);
  if (lane == 0) en[row] = s;
}

// ---------------- precompute f16(hi) codebook, fragment-linear ----------------
__global__ __launch_bounds__(256) void vq_split_cb(const float* __restrict__ c0,
                                                   const float* __restrict__ c1,
                                                   const float* __restrict__ c2,
                                                   half8* __restrict__ bh) {
  const int t = blockIdx.x * 256 + threadIdx.x;    // 0..36863
  const int lvl = t / 12288;
  const int rem = t - lvl * 12288;
  const int kt = rem >> 10;
  const int f = (rem >> 6) & 15;
  const int lane = rem & 63;
  const int code = (f >> 1) * 32 + (lane & 31);
  const int k0 = kt * 32 + (f & 1) * 16 + (lane >> 5) * 8;
  const float* cb = (lvl == 0) ? c0 : ((lvl == 1) ? c1 : c2);
  const float4 a = ld4(cb + code * D_MODEL + k0);
  const float4 b = ld4(cb + code * D_MODEL + k0 + 4);
  bh[t] = cvt8h(a, b);
}

#define XN8(v0, v1, v2, v3)                                                     \
  xn_part = fmaf(v0.x, v0.x, xn_part); xn_part = fmaf(v0.y, v0.y, xn_part);     \
  xn_part = fmaf(v0.z, v0.z, xn_part); xn_part = fmaf(v0.w, v0.w, xn_part);     \
  xn_part = fmaf(v1.x, v1.x, xn_part); xn_part = fmaf(v1.y, v1.y, xn_part);     \
  xn_part = fmaf(v1.z, v1.z, xn_part); xn_part = fmaf(v1.w, v1.w, xn_part);     \
  xn_part = fmaf(v2.x, v2.x, xn_part); xn_part = fmaf(v2.y, v2.y, xn_part);     \
  xn_part = fmaf(v2.z, v2.z, xn_part); xn_part = fmaf(v2.w, v2.w, xn_part);     \
  xn_part = fmaf(v3.x, v3.x, xn_part); xn_part = fmaf(v3.y, v3.y, xn_part);     \
  xn_part = fmaf(v3.z, v3.z, xn_part); xn_part = fmaf(v3.w, v3.w, xn_part);

// ---------------- fused main VQ kernel, all 3 levels ----------------
// 4608 blocks (XCD-swizzled), 256 threads = 4 waves (2M x 2N), 3 blocks/CU.
// A: global->reg->f16, 2-deep prefetch via named slots (register deps only).
// B: global->reg direct (wave-private fragment stream, L2-hot). No K-loop barriers.
__global__ __launch_bounds__(256, 3) void vq_mfma_all(
    const float* __restrict__ l0, const float* __restrict__ l1,
    const float* __restrict__ l2,
    const float* __restrict__ en_all,
    const half8* __restrict__ bh_pre,
    float* __restrict__ out, float* __restrict__ dmin_all,
    float* __restrict__ xn_all,
    int* __restrict__ list0, int* __restrict__ list1, int* __restrict__ list2,
    int* __restrict__ counts) {
  __shared__ __align__(16) unsigned char smem[40960];   // epilogue only
  float*  scanbuf = (float*)smem;           //     0..32768  [32][256]
  float4* red     = (float4*)(smem + 32768);// 32768..36864  [32][8]
  float*  en_s    = (float*)(smem + 36864); // 36864..37888  [256]
  float4* rowres  = (float4*)(smem + 37888);// 37888..38912  [64]
  float*  xns     = (float*)(smem + 38912); // 38912..39168  [64]

  const int swz = (blockIdx.x & 7) * 576 + (blockIdx.x >> 3);
  int lvl, blk;
  if (swz < 512)       { lvl = 0; blk = swz; }
  else if (swz < 2560) { lvl = 1; blk = swz - 512; }
  else                 { lvl = 2; blk = swz - 2560; }
  const float* x  = (lvl == 0) ? l0 : ((lvl == 1) ? l1 : l2);
  const float* en = en_all + lvl * 256;
  const half8* bh = bh_pre + lvl * 12288;
  const long ioff = (lvl == 0) ? 0 : ((lvl == 1) ? 32768 : 163840);
  float* out_idx = out + ioff;
  float* dmin_lvl = dmin_all + ioff;
  float* xn_lvl   = xn_all + ioff;
  int* list = (lvl == 0) ? list0 : ((lvl == 1) ? list1 : list2);
  int* cnt  = counts + lvl;

  const int tid = threadIdx.x;
  const int lane = tid & 63;
  const int w = tid >> 6, wm = w >> 1, wn = w & 1;
  const int c31 = lane & 31, h = lane >> 5;
  const long m0 = (long)blk * BM;

  const float* ap = x + (m0 + wm * 32 + c31) * (long)D_MODEL + h * 8;
  const half8* bhw = bh + wn * 512 + lane;   // wave-private fragment stream

  f32x16 acc[4];
#pragma unroll
  for (int n = 0; n < 4; ++n)
#pragma unroll
    for (int i = 0; i < 16; ++i) acc[n][i] = 0.f;

  float xn_part = 0.f;

  // prologue: L(0)->slot0, L(1)->slot1, cvt L(0)
  float4 fA0 = ld4(ap + 0),  fA1 = ld4(ap + 4),  fA2 = ld4(ap + 16), fA3 = ld4(ap + 20);
  float4 fB0 = ld4(ap + 32), fB1 = ld4(ap + 36), fB2 = ld4(ap + 48), fB3 = ld4(ap + 52);
  XN8(fA0, fA1, fA2, fA3)
  half8 ahc0 = cvt8h(fA0, fA1);
  half8 ahc1 = cvt8h(fA2, fA3);

#pragma unroll
  for (int kt = 0; kt < NKT; ++kt) {
    // issue L(kt+2) into slot[kt&1] (its raw regs were cvt'd at end of step kt-1)
    if (kt + 2 < NKT) {
      const int ko = (kt + 2) * 32;
      if ((kt & 1) == 0) {
        fA0 = ld4(ap + ko); fA1 = ld4(ap + ko + 4);
        fA2 = ld4(ap + ko + 16); fA3 = ld4(ap + ko + 20);
      } else {
        fB0 = ld4(ap + ko); fB1 = ld4(ap + ko + 4);
        fB2 = ld4(ap + ko + 16); fB3 = ld4(ap + ko + 20);
      }
    }
    // B(kt) fragments -> registers (8 coalesced dwordx4, L2-hot)
    half8 b0 = bhw[kt * 1024 + 0 * 64];
    half8 b1 = bhw[kt * 1024 + 1 * 64];
    half8 b2 = bhw[kt * 1024 + 2 * 64];
    half8 b3 = bhw[kt * 1024 + 3 * 64];
    half8 b4 = bhw[kt * 1024 + 4 * 64];
    half8 b5 = bhw[kt * 1024 + 5 * 64];
    half8 b6 = bhw[kt * 1024 + 6 * 64];
    half8 b7 = bhw[kt * 1024 + 7 * 64];
    // MFMA(kt)
    acc[0] = __builtin_amdgcn_mfma_f32_32x32x16_f16(ahc0, b0, acc[0], 0, 0, 0);
    acc[0] = __builtin_amdgcn_mfma_f32_32x32x16_f16(ahc1, b1, acc[0], 0, 0, 0);
    acc[1] = __builtin_amdgcn_mfma_f32_32x32x16_f16(ahc0, b2, acc[1], 0, 0, 0);
    acc[1] = __builtin_amdgcn_mfma_f32_32x32x16_f16(ahc1, b3, acc[1], 0, 0, 0);
    acc[2] = __builtin_amdgcn_mfma_f32_32x32x16_f16(ahc0, b4, acc[2], 0, 0, 0);
    acc[2] = __builtin_amdgcn_mfma_f32_32x32x16_f16(ahc1, b5, acc[2], 0, 0, 0);
    acc[3] = __builtin_amdgcn_mfma_f32_32x32x16_f16(ahc0, b6, acc[3], 0, 0, 0);
    acc[3] = __builtin_amdgcn_mfma_f32_32x32x16_f16(ahc1, b7, acc[3], 0, 0, 0);
    // cvt L(kt+1) from slot[(kt+1)&1]
    if (kt + 1 < NKT) {
      if ((kt & 1) == 0) {
        XN8(fB0, fB1, fB2, fB3)
        ahc0 = cvt8h(fB0, fB1);
        ahc1 = cvt8h(fB2, fB3);
      } else {
        XN8(fA0, fA1, fA2, fA3)
        ahc0 = cvt8h(fA0, fA1);
        ahc1 = cvt8h(fA2, fA3);
      }
    }
  }

  // ---- row norms: lanes h=0/1 hold halves; pair via shfl; wn==0 writes ----
  {
    const float xr = xn_part + __shfl_xor(xn_part, 32, 64);
    if (wn == 0 && lane < 32) xns[wm * 32 + lane] = xr;
  }
  en_s[tid] = en[tid];

  // ---- epilogue: approx top-2 per row via LDS scan, 2 batches of 32 rows ----
#pragma unroll 1
  for (int b = 0; b < 2; ++b) {
    __syncthreads();
    if (wm == b) {
#pragma unroll
      for (int n = 0; n < 4; ++n) {
        const int colbase = wn * 128 + n * 32 + c31;
#pragma unroll
        for (int rr = 0; rr < 16; ++rr) {
          const int row_b = (rr & 3) + ((rr >> 2) << 3) + (h << 2);
          const int p = colbase ^ ((row_b & 3) << 3);
          scanbuf[row_b * 256 + p] = fmaf(-2.f, acc[n][rr], en_s[colbase]);
        }
      }
    }
    __syncthreads();
    {
      const int srow = tid >> 3, chunk = tid & 7;
      float b1 = 1e30f, b2 = 1e30f; int i1 = 0, i2 = 0;
#pragma unroll
      for (int u = 0; u < 32; ++u) {
        const int col = chunk + u * 8;
        const float d = scanbuf[srow * 256 + (col ^ ((srow & 3) << 3))];
        if (d < b1) { b2 = b1; i2 = i1; b1 = d; i1 = col; }
        else if (d < b2) { b2 = d; i2 = col; }
      }
      red[srow * 8 + chunk] = make_float4(b1, __int_as_float(i1), b2, __int_as_float(i2));
    }
    __syncthreads();
    if (tid < 32) {
      float4 q = red[tid * 8 + 0];
      float fb1 = q.x, fb2 = q.z;
      int fi1 = __float_as_int(q.y), fi2 = __float_as_int(q.w);
#pragma unroll
      for (int c = 1; c < 8; ++c) {
        q = red[tid * 8 + c];
        const float c1 = q.x, c2 = q.z;
        const int j1 = __float_as_int(q.y), j2 = __float_as_int(q.w);
        if (c1 < fb1 || (c1 == fb1 && j1 < fi1)) {
          if (fb1 < c2 || (fb1 == c2 && fi1 < j2)) { fb2 = fb1; fi2 = fi1; }
          else { fb2 = c2; fi2 = j2; }
          fb1 = c1; fi1 = j1;
        } else if (c1 < fb2 || (c1 == fb2 && j1 < fi2)) { fb2 = c1; fi2 = j1; }
      }
      rowres[b * 32 + tid] = make_float4(fb1, __int_as_float(fi1), fb2, __int_as_float(fi2));
    }
  }
  __syncthreads();

  // ---- finalize: write approx results; flag + compact near-ties ----
  if (tid < BM) {
    const int m = tid;
    const float4 qv = rowres[m];
    const float fb1 = qv.x, fb2 = qv.z;
    const int fi1 = __float_as_int(qv.y);
    const float xn = xns[m];
    out_idx[m0 + m] = (float)fi1;
    dmin_lvl[m0 + m] = xn + fb1;
    xn_lvl[m0 + m] = xn;
    const bool flg = (fb2 - fb1 < RTAU);
    const unsigned long long mask = __ballot(flg);
    const int nf = __popcll(mask);
    int base = 0;
    if (tid == 0 && nf) base = atomicAdd(cnt, nf);
    base = __shfl(base, 0, 64);
    if (flg) {
      const int pos = __popcll(mask & ((1ull << tid) - 1ull));
      list[base + pos] = (int)(m0 + m);
    }
  }
}

// ---------------- fused DOUBLE-precision rescue, all 3 levels ----------------
// Updates out_idx + dmin only (q handled by vq_gather afterwards).
__global__ __launch_bounds__(256) void vq_rescue_all(
    const float* __restrict__ l0, const float* __restrict__ l1,
    const float* __restrict__ l2, const float* __restrict__ c0,
    const float* __restrict__ c1, const float* __restrict__ c2,
    const int* __restrict__ list0, const int* __restrict__ list1,
    const int* __restrict__ list2, const int* __restrict__ counts,
    float* __restrict__ out, float* __restrict__ dmin_all,
    const float* __restrict__ xn_all) {
  __shared__ float xs[8][D_MODEL];     // 12 KB
  __shared__ double dall[8][256];      // 16 KB
  __shared__ int rows_s[8];
  __shared__ float xns_s[8];

  const int lvl = blockIdx.x >> 10;         // 1024 blocks per level
  const int sb  = blockIdx.x & 1023;
  const float* x  = (lvl == 0) ? l0 : ((lvl == 1) ? l1 : l2);
  const float* cb = (lvl == 0) ? c0 : ((lvl == 1) ? c1 : c2);
  const int* list = (lvl == 0) ? list0 : ((lvl == 1) ? list1 : list2);
  const long ioff = (lvl == 0) ? 0 : ((lvl == 1) ? 32768 : 163840);
  float* out_idx = out + ioff;
  float* dmin_lvl = dmin_all + ioff;
  const float* xn_lvl = xn_all + ioff;

  const int tid = threadIdx.x;              // = code index
  const int count = counts[lvl];
  const int nch = (count + 7) >> 3;
  const int w = tid >> 6, lane = tid & 63;
  const float* crow = cb + (long)tid * D_MODEL;

  // per-code fp64 norm: computed ONCE (r13: was recomputed every chunk)
  double en_d = 0.0;
  for (int k = 0; k < D_MODEL; ++k) {
    const double cd = (double)crow[k];
    en_d = fma(cd, cd, en_d);
  }

  for (int c = sb; c < nch; c += 1024) {
    const int base = c << 3;
    const int R = min(8, count - base);
    if (tid < 8) {
      const int j = min(tid, R - 1);
      const int r = list[base + j];
      rows_s[tid] = r;
      xns_s[tid] = xn_lvl[r];
    }
    __syncthreads();
#pragma unroll
    for (int r = 0; r < 8; ++r)
      if (tid < NSEG) *(float4*)&xs[r][tid * 4] = ld4(x + (long)rows_s[r] * D_MODEL + tid * 4);
    __syncthreads();

    double dot[8] = {0.0, 0.0, 0.0, 0.0, 0.0, 0.0, 0.0, 0.0};
    for (int k = 0; k < D_MODEL; ++k) {
      const double cd = (double)crow[k];
#pragma unroll
      for (int r = 0; r < 8; ++r)
        dot[r] = fma(cd, (double)xs[r][k], dot[r]);
    }
#pragma unroll
    for (int r = 0; r < 8; ++r)
      dall[r][tid] = fma(-2.0, dot[r], en_d);
    __syncthreads();

#pragma unroll
    for (int rr = 0; rr < 2; ++rr) {
      const int r = w + rr * 4;
      if (r < R) {
        double best = dall[r][lane]; int bidx = lane;
#pragma unroll
        for (int u = 1; u < 4; ++u) {
          const int code = lane + u * 64;     // ascending per thread
          const double d = dall[r][code];
          if (d < best) { best = d; bidx = code; }
        }
        for (int mm = 1; mm < 64; mm <<= 1) {
          const double ov = __shfl_xor(best, mm, 64);
          const int oi = __shfl_xor(bidx, mm, 64);
          if (ov < best || (ov == best && oi < bidx)) { best = ov; bidx = oi; }
        }
        if (lane == 0) {
          const int row = rows_s[r];
          out_idx[row] = (float)bidx;
          dmin_lvl[row] = xns_s[r] + (float)best;
        }
      }
    }
    __syncthreads();
  }
}

// ---------------- streaming q-gather (after rescue; final idx) ----------------
// 4608 blocks x 64 rows. thread: row = base+(tid>>2), quarter = tid&3;
// iteration u copies seg 4u+quarter -> 64B-contiguous chunks per row-quad.
__global__ __launch_bounds__(256) void vq_gather(
    const float* __restrict__ c0, const float* __restrict__ c1,
    const float* __restrict__ c2, float* __restrict__ out) {
  __shared__ int idx_s[BM];
  int lvl, blk;
  if (blockIdx.x < 512)       { lvl = 0; blk = blockIdx.x; }
  else if (blockIdx.x < 2560) { lvl = 1; blk = blockIdx.x - 512; }
  else                        { lvl = 2; blk = blockIdx.x - 2560; }
  const float* cb = (lvl == 0) ? c0 : ((lvl == 1) ? c1 : c2);
  const long ioff = (lvl == 0) ? 0 : ((lvl == 1) ? 32768 : 163840);
  const float* out_idx = out + ioff;
  float* out_q = out + ((lvl == 0) ? 294913L : ((lvl == 1) ? 12877825L : 63209473L));
  const long m0 = (long)blk * BM;

  const int tid = threadIdx.x;
  if (tid < BM) idx_s[tid] = (int)out_idx[m0 + tid];
  __syncthreads();

  const int row = tid >> 2;
  const int qt  = tid & 3;
  const float* src = cb + (long)idx_s[row] * D_MODEL + qt * 4;
  float* dst = out_q + (m0 + row) * (long)D_MODEL + qt * 4;
#pragma unroll
  for (int u = 0; u < 24; ++u)
    *(float4*)(dst + u * 16) = ld4(src + u * 16);
}

// ---------------- deterministic loss reduce (after rescue) ----------------
__global__ __launch_bounds__(256) void loss_stage1(const float* __restrict__ dmin,
                                                   double* __restrict__ lp) {
  const int b = blockIdx.x;           // 576 blocks x 512 rows
  const int tid = threadIdx.x;
  const long r0 = (long)b * 512;
  __shared__ double sh[256];
  sh[tid] = (double)dmin[r0 + tid] + (double)dmin[r0 + 256 + tid];
  __syncthreads();
  for (int st = 128; st > 0; st >>= 1) {
    if (tid < st) sh[tid] += sh[tid + st];
    __syncthreads();
  }
  if (tid == 0) {
    double scale;
    if (b < 64)       scale = 0.05 / (32768.0 * 384.0);
    else if (b < 320) scale = 0.25 / (131072.0 * 384.0);
    else              scale = 0.60 / (131072.0 * 384.0);
    lp[b] = sh[0] * scale;
  }
}

__global__ __launch_bounds__(256) void loss_stage2(const double* __restrict__ lp,
                                                   float* __restrict__ out_loss) {
  const int tid = threadIdx.x;
  __shared__ double sh[256];
  sh[tid] = lp[tid] + lp[tid + 256] + ((tid < 64) ? lp[tid + 512] : 0.0);
  __syncthreads();
  for (int st = 128; st > 0; st >>= 1) {
    if (tid < st) sh[tid] += sh[tid + st];
    __syncthreads();
  }
  if (tid == 0) out_loss[0] = (float)sh[0];
}

extern "C" void kernel_launch(void* const* d_in, const int* in_sizes, int n_in,
                              void* d_out, int out_size, void* d_ws, size_t ws_size,
                              hipStream_t stream) {
  const float* l0 = (const float*)d_in[0];
  const float* l1 = (const float*)d_in[1];
  const float* l2 = (const float*)d_in[2];
  const float* c0 = (const float*)d_in[3];
  const float* c1 = (const float*)d_in[4];
  const float* c2 = (const float*)d_in[5];
  float* out = (float*)d_out;

  float* wsf = (float*)d_ws;
  int*   counts   = (int*)wsf;               // 4 ints
  float* en       = wsf + 4;                 // 768
  float* dmin_all = wsf + 772;               // 294912
  float* xn_all   = wsf + 295684;            // 294912
  int*   list0    = (int*)(wsf + 590596);    // cap 32768 (= all rows)
  int*   list1    = (int*)(wsf + 623364);    // cap 131072
  int*   list2    = (int*)(wsf + 754436);    // cap 131072
  double* lp      = (double*)(wsf + 885508); // 576 doubles
  half8* bh_pre   = (half8*)(wsf + 886660);  // 36864 half8 (16B-aligned)

  vq_norms<<<768, 64, 0, stream>>>(c0, c1, c2, en, counts);
  vq_split_cb<<<144, 256, 0, stream>>>(c0, c1, c2, bh_pre);

  vq_mfma_all<<<4608, 256, 0, stream>>>(l0, l1, l2, en, bh_pre, out,
                                        dmin_all, xn_all,
                                        list0, list1, list2, counts);

  vq_rescue_all<<<3072, 256, 0, stream>>>(l0, l1, l2, c0, c1, c2,
                                          list0, list1, list2, counts,
                                          out, dmin_all, xn_all);

  vq_gather<<<4608, 256, 0, stream>>>(c0, c1, c2, out);

  loss_stage1<<<576, 256, 0, stream>>>(dmin_all, lp);
  loss_stage2<<<1, 256, 0, stream>>>(lp, out + 294912);
}

// Round 15
// 458.555 us; speedup vs baseline: 1.3786x; 1.3786x over previous
//
#include <hip/hip_runtime.h>

// SpatialHRVQTokenizer: 3-level VQ forward.
// Main GEMM: 3-term f16-split MFMA (hh+hl+lh, r4-r7-proven), B global->register
// (no K-loop barriers, r13-proven race-free). Rows with approx top-2 gap <
// RTAU=0.01 re-solved in fp64 (r10-proven). Streaming coalesced q-gather.
// Output (flat fp32): idx0[0,32768) idx1[...,163840) idx2[...,294912)
//   loss[294912]  q0[294913..)  q1[12877825..)  q2[63209473..)

typedef _Float16 half8 __attribute__((ext_vector_type(8)));
typedef float f32x16 __attribute__((ext_vector_type(16)));

#define D_MODEL 384
#define NSEG 96
#define NKT 12
#define BM 64
#define RTAU 0.01f

__device__ __forceinline__ float4 ld4(const float* p) { return *(const float4*)p; }

__device__ __forceinline__ void cvt8(const float4& a, const float4& b, half8& hi, half8& lo) {
  const float v[8] = {a.x, a.y, a.z, a.w, b.x, b.y, b.z, b.w};
#pragma unroll
  for (int u = 0; u < 8; ++u) {
    _Float16 h = (_Float16)v[u];
    hi[u] = h;
    lo[u] = (_Float16)(v[u] - (float)h);
  }
}

// ---------------- code norms + counter zeroing ----------------
__global__ __launch_bounds__(64) void vq_norms(const float* __restrict__ c0,
                                               const float* __restrict__ c1,
                                               const float* __restrict__ c2,
                                               float* __restrict__ en,
                                               int* __restrict__ counts) {
  if (blockIdx.x == 0 && threadIdx.x < 4) counts[threadIdx.x] = 0;
  const int row = blockIdx.x;  // 0..767
  const float* cb = (row < 256) ? c0 : ((row < 512) ? c1 : c2);
  const int n = row & 255;
  const int lane = threadIdx.x;
  const float* r = cb + (size_t)n * D_MODEL;
  float s = 0.f;
  for (int c = lane; c < D_MODEL; c += 64) s = fmaf(r[c], r[c], s);
  for (int m = 1; m < 64; m <<= 1) s += __shfl_xor(s, m, 64);
  if (lane == 0) en[row] = s;
}

// ---------------- precompute f16 hi+lo codebook, fragment-linear ----------------
// index t = ((lvl*12 + kt)*16 + f)*64 + lane ; f = nt*2+kc
// code = nt*32 + (lane&31) ; k0 = kt*32 + kc*16 + (lane>>5)*8
__global__ __launch_bounds__(256) void vq_split_cb(const float* __restrict__ c0,
                                                   const float* __restrict__ c1,
                                                   const float* __restrict__ c2,
                                                   half8* __restrict__ bh,
                                                   half8* __restrict__ bl) {
  const int t = blockIdx.x * 256 + threadIdx.x;    // 0..36863
  const int lvl = t / 12288;
  const int rem = t - lvl * 12288;
  const int kt = rem >> 10;
  const int f = (rem >> 6) & 15;
  const int lane = rem & 63;
  const int code = (f >> 1) * 32 + (lane & 31);
  const int k0 = kt * 32 + (f & 1) * 16 + (lane >> 5) * 8;
  const float* cb = (lvl == 0) ? c0 : ((lvl == 1) ? c1 : c2);
  const float4 a = ld4(cb + code * D_MODEL + k0);
  const float4 b = ld4(cb + code * D_MODEL + k0 + 4);
  half8 hv, lv;
  cvt8(a, b, hv, lv);
  bh[t] = hv;
  bl[t] = lv;
}

#define XN8(v0, v1, v2, v3)                                                     \
  xn_part = fmaf(v0.x, v0.x, xn_part); xn_part = fmaf(v0.y, v0.y, xn_part);     \
  xn_part = fmaf(v0.z, v0.z, xn_part); xn_part = fmaf(v0.w, v0.w, xn_part);     \
  xn_part = fmaf(v1.x, v1.x, xn_part); xn_part = fmaf(v1.y, v1.y, xn_part);     \
  xn_part = fmaf(v1.z, v1.z, xn_part); xn_part = fmaf(v1.w, v1.w, xn_part);     \
  xn_part = fmaf(v2.x, v2.x, xn_part); xn_part = fmaf(v2.y, v2.y, xn_part);     \
  xn_part = fmaf(v2.z, v2.z, xn_part); xn_part = fmaf(v2.w, v2.w, xn_part);     \
  xn_part = fmaf(v3.x, v3.x, xn_part); xn_part = fmaf(v3.y, v3.y, xn_part);     \
  xn_part = fmaf(v3.z, v3.z, xn_part); xn_part = fmaf(v3.w, v3.w, xn_part);

// ---------------- fused main VQ kernel, all 3 levels ----------------
// 4608 blocks (XCD-swizzled), 256 threads = 4 waves (2M x 2N), 3 blocks/CU.
// A: global->reg->f16 hi/lo, 2-slot prefetch (register deps only).
// B: global->reg hi+lo fragment streams (wave-private, L2-hot). No K-loop barriers.
// dot ~= ah*bh + ah*bl + al*bh (lo*lo dropped; fp64 rescue covers RTAU window).
__global__ __launch_bounds__(256, 3) void vq_mfma_all(
    const float* __restrict__ l0, const float* __restrict__ l1,
    const float* __restrict__ l2,
    const float* __restrict__ en_all,
    const half8* __restrict__ bh_pre, const half8* __restrict__ bl_pre,
    float* __restrict__ out, float* __restrict__ dmin_all,
    float* __restrict__ xn_all,
    int* __restrict__ list0, int* __restrict__ list1, int* __restrict__ list2,
    int* __restrict__ counts) {
  __shared__ __align__(16) unsigned char smem[40960];   // epilogue only
  float*  scanbuf = (float*)smem;           //     0..32768  [32][256]
  float4* red     = (float4*)(smem + 32768);// 32768..36864  [32][8]
  float*  en_s    = (float*)(smem + 36864); // 36864..37888  [256]
  float4* rowres  = (float4*)(smem + 37888);// 37888..38912  [64]
  float*  xns     = (float*)(smem + 38912); // 38912..39168  [64]

  const int swz = (blockIdx.x & 7) * 576 + (blockIdx.x >> 3);
  int lvl, blk;
  if (swz < 512)       { lvl = 0; blk = swz; }
  else if (swz < 2560) { lvl = 1; blk = swz - 512; }
  else                 { lvl = 2; blk = swz - 2560; }
  const float* x  = (lvl == 0) ? l0 : ((lvl == 1) ? l1 : l2);
  const float* en = en_all + lvl * 256;
  const long ioff = (lvl == 0) ? 0 : ((lvl == 1) ? 32768 : 163840);
  float* out_idx = out + ioff;
  float* dmin_lvl = dmin_all + ioff;
  float* xn_lvl   = xn_all + ioff;
  int* list = (lvl == 0) ? list0 : ((lvl == 1) ? list1 : list2);
  int* cnt  = counts + lvl;

  const int tid = threadIdx.x;
  const int lane = tid & 63;
  const int w = tid >> 6, wm = w >> 1, wn = w & 1;
  const int c31 = lane & 31, h = lane >> 5;
  const long m0 = (long)blk * BM;

  const float* ap = x + (m0 + wm * 32 + c31) * (long)D_MODEL + h * 8;
  const half8* bhw = bh_pre + lvl * 12288 + wn * 512 + lane;  // hi stream
  const half8* blw = bl_pre + lvl * 12288 + wn * 512 + lane;  // lo stream

  f32x16 acc[4];
#pragma unroll
  for (int n = 0; n < 4; ++n)
#pragma unroll
    for (int i = 0; i < 16; ++i) acc[n][i] = 0.f;

  float xn_part = 0.f;

  // prologue: L(0)->slot0, L(1)->slot1, cvt L(0)
  float4 fA0 = ld4(ap + 0),  fA1 = ld4(ap + 4),  fA2 = ld4(ap + 16), fA3 = ld4(ap + 20);
  float4 fB0 = ld4(ap + 32), fB1 = ld4(ap + 36), fB2 = ld4(ap + 48), fB3 = ld4(ap + 52);
  XN8(fA0, fA1, fA2, fA3)
  half8 ahc0, alc0, ahc1, alc1;
  cvt8(fA0, fA1, ahc0, alc0);
  cvt8(fA2, fA3, ahc1, alc1);

#pragma unroll
  for (int kt = 0; kt < NKT; ++kt) {
    // issue L(kt+2) into slot[kt&1] (raw regs consumed by cvt at end of step kt-1)
    if (kt + 2 < NKT) {
      const int ko = (kt + 2) * 32;
      if ((kt & 1) == 0) {
        fA0 = ld4(ap + ko); fA1 = ld4(ap + ko + 4);
        fA2 = ld4(ap + ko + 16); fA3 = ld4(ap + ko + 20);
      } else {
        fB0 = ld4(ap + ko); fB1 = ld4(ap + ko + 4);
        fB2 = ld4(ap + ko + 16); fB3 = ld4(ap + ko + 20);
      }
    }
    // MFMA(kt): per n-tile load 4 fragments (hi/lo x kc0/kc1), 6 MFMAs
#pragma unroll
    for (int n = 0; n < 4; ++n) {
      half8 bh0 = bhw[kt * 1024 + (2 * n + 0) * 64];
      half8 bh1 = bhw[kt * 1024 + (2 * n + 1) * 64];
      half8 bl0 = blw[kt * 1024 + (2 * n + 0) * 64];
      half8 bl1 = blw[kt * 1024 + (2 * n + 1) * 64];
      acc[n] = __builtin_amdgcn_mfma_f32_32x32x16_f16(ahc0, bh0, acc[n], 0, 0, 0);
      acc[n] = __builtin_amdgcn_mfma_f32_32x32x16_f16(ahc1, bh1, acc[n], 0, 0, 0);
      acc[n] = __builtin_amdgcn_mfma_f32_32x32x16_f16(ahc0, bl0, acc[n], 0, 0, 0);
      acc[n] = __builtin_amdgcn_mfma_f32_32x32x16_f16(ahc1, bl1, acc[n], 0, 0, 0);
      acc[n] = __builtin_amdgcn_mfma_f32_32x32x16_f16(alc0, bh0, acc[n], 0, 0, 0);
      acc[n] = __builtin_amdgcn_mfma_f32_32x32x16_f16(alc1, bh1, acc[n], 0, 0, 0);
    }
    // cvt L(kt+1) from slot[(kt+1)&1]
    if (kt + 1 < NKT) {
      if ((kt & 1) == 0) {
        XN8(fB0, fB1, fB2, fB3)
        cvt8(fB0, fB1, ahc0, alc0);
        cvt8(fB2, fB3, ahc1, alc1);
      } else {
        XN8(fA0, fA1, fA2, fA3)
        cvt8(fA0, fA1, ahc0, alc0);
        cvt8(fA2, fA3, ahc1, alc1);
      }
    }
  }

  // ---- row norms: lanes h=0/1 hold halves; pair via shfl; wn==0 writes ----
  {
    const float xr = xn_part + __shfl_xor(xn_part, 32, 64);
    if (wn == 0 && lane < 32) xns[wm * 32 + lane] = xr;
  }
  en_s[tid] = en[tid];

  // ---- epilogue: approx top-2 per row via LDS scan, 2 batches of 32 rows ----
#pragma unroll 1
  for (int b = 0; b < 2; ++b) {
    __syncthreads();
    if (wm == b) {
#pragma unroll
      for (int n = 0; n < 4; ++n) {
        const int colbase = wn * 128 + n * 32 + c31;
#pragma unroll
        for (int rr = 0; rr < 16; ++rr) {
          const int row_b = (rr & 3) + ((rr >> 2) << 3) + (h << 2);
          const int p = colbase ^ ((row_b & 3) << 3);
          scanbuf[row_b * 256 + p] = fmaf(-2.f, acc[n][rr], en_s[colbase]);
        }
      }
    }
    __syncthreads();
    {
      const int srow = tid >> 3, chunk = tid & 7;
      float b1 = 1e30f, b2 = 1e30f; int i1 = 0, i2 = 0;
#pragma unroll
      for (int u = 0; u < 32; ++u) {
        const int col = chunk + u * 8;
        const float d = scanbuf[srow * 256 + (col ^ ((srow & 3) << 3))];
        if (d < b1) { b2 = b1; i2 = i1; b1 = d; i1 = col; }
        else if (d < b2) { b2 = d; i2 = col; }
      }
      red[srow * 8 + chunk] = make_float4(b1, __int_as_float(i1), b2, __int_as_float(i2));
    }
    __syncthreads();
    if (tid < 32) {
      float4 q = red[tid * 8 + 0];
      float fb1 = q.x, fb2 = q.z;
      int fi1 = __float_as_int(q.y), fi2 = __float_as_int(q.w);
#pragma unroll
      for (int c = 1; c < 8; ++c) {
        q = red[tid * 8 + c];
        const float c1 = q.x, c2 = q.z;
        const int j1 = __float_as_int(q.y), j2 = __float_as_int(q.w);
        if (c1 < fb1 || (c1 == fb1 && j1 < fi1)) {
          if (fb1 < c2 || (fb1 == c2 && fi1 < j2)) { fb2 = fb1; fi2 = fi1; }
          else { fb2 = c2; fi2 = j2; }
          fb1 = c1; fi1 = j1;
        } else if (c1 < fb2 || (c1 == fb2 && j1 < fi2)) { fb2 = c1; fi2 = j1; }
      }
      rowres[b * 32 + tid] = make_float4(fb1, __int_as_float(fi1), fb2, __int_as_float(fi2));
    }
  }
  __syncthreads();

  // ---- finalize: write approx results; flag + compact near-ties ----
  if (tid < BM) {
    const int m = tid;
    const float4 qv = rowres[m];
    const float fb1 = qv.x, fb2 = qv.z;
    const int fi1 = __float_as_int(qv.y);
    const float xn = xns[m];
    out_idx[m0 + m] = (float)fi1;
    dmin_lvl[m0 + m] = xn + fb1;
    xn_lvl[m0 + m] = xn;
    const bool flg = (fb2 - fb1 < RTAU);
    const unsigned long long mask = __ballot(flg);
    const int nf = __popcll(mask);
    int base = 0;
    if (tid == 0 && nf) base = atomicAdd(cnt, nf);
    base = __shfl(base, 0, 64);
    if (flg) {
      const int pos = __popcll(mask & ((1ull << tid) - 1ull));
      list[base + pos] = (int)(m0 + m);
    }
  }
}

// ---------------- fused DOUBLE-precision rescue, all 3 levels ----------------
// Updates out_idx + dmin only (q handled by vq_gather afterwards).
__global__ __launch_bounds__(256) void vq_rescue_all(
    const float* __restrict__ l0, const float* __restrict__ l1,
    const float* __restrict__ l2, const float* __restrict__ c0,
    const float* __restrict__ c1, const float* __restrict__ c2,
    const int* __restrict__ list0, const int* __restrict__ list1,
    const int* __restrict__ list2, const int* __restrict__ counts,
    float* __restrict__ out, float* __restrict__ dmin_all,
    const float* __restrict__ xn_all) {
  __shared__ float xs[8][D_MODEL];     // 12 KB
  __shared__ double dall[8][256];      // 16 KB
  __shared__ int rows_s[8];
  __shared__ float xns_s[8];

  const int lvl = blockIdx.x >> 10;         // 1024 blocks per level
  const int sb  = blockIdx.x & 1023;
  const float* x  = (lvl == 0) ? l0 : ((lvl == 1) ? l1 : l2);
  const float* cb = (lvl == 0) ? c0 : ((lvl == 1) ? c1 : c2);
  const int* list = (lvl == 0) ? list0 : ((lvl == 1) ? list1 : list2);
  const long ioff = (lvl == 0) ? 0 : ((lvl == 1) ? 32768 : 163840);
  float* out_idx = out + ioff;
  float* dmin_lvl = dmin_all + ioff;
  const float* xn_lvl = xn_all + ioff;

  const int tid = threadIdx.x;              // = code index
  const int count = counts[lvl];
  const int nch = (count + 7) >> 3;
  const int w = tid >> 6, lane = tid & 63;
  const float* crow = cb + (long)tid * D_MODEL;

  if (sb >= nch) return;

  // per-code fp64 norm: computed once
  double en_d = 0.0;
  for (int k = 0; k < D_MODEL; ++k) {
    const double cd = (double)crow[k];
    en_d = fma(cd, cd, en_d);
  }

  for (int c = sb; c < nch; c += 1024) {
    const int base = c << 3;
    const int R = min(8, count - base);
    if (tid < 8) {
      const int j = min(tid, R - 1);
      const int r = list[base + j];
      rows_s[tid] = r;
      xns_s[tid] = xn_lvl[r];
    }
    __syncthreads();
#pragma unroll
    for (int r = 0; r < 8; ++r)
      if (tid < NSEG) *(float4*)&xs[r][tid * 4] = ld4(x + (long)rows_s[r] * D_MODEL + tid * 4);
    __syncthreads();

    double dot[8] = {0.0, 0.0, 0.0, 0.0, 0.0, 0.0, 0.0, 0.0};
    for (int k = 0; k < D_MODEL; ++k) {
      const double cd = (double)crow[k];
#pragma unroll
      for (int r = 0; r < 8; ++r)
        dot[r] = fma(cd, (double)xs[r][k], dot[r]);
    }
#pragma unroll
    for (int r = 0; r < 8; ++r)
      dall[r][tid] = fma(-2.0, dot[r], en_d);
    __syncthreads();

#pragma unroll
    for (int rr = 0; rr < 2; ++rr) {
      const int r = w + rr * 4;
      if (r < R) {
        double best = dall[r][lane]; int bidx = lane;
#pragma unroll
        for (int u = 1; u < 4; ++u) {
          const int code = lane + u * 64;     // ascending per thread
          const double d = dall[r][code];
          if (d < best) { best = d; bidx = code; }
        }
        for (int mm = 1; mm < 64; mm <<= 1) {
          const double ov = __shfl_xor(best, mm, 64);
          const int oi = __shfl_xor(bidx, mm, 64);
          if (ov < best || (ov == best && oi < bidx)) { best = ov; bidx = oi; }
        }
        if (lane == 0) {
          const int row = rows_s[r];
          out_idx[row] = (float)bidx;
          dmin_lvl[row] = xns_s[r] + (float)best;
        }
      }
    }
    __syncthreads();
  }
}

// ---------------- streaming q-gather (after rescue; final idx) ----------------
// 4608 blocks x 64 rows; writes are FULLY LINEAR: dst float4 index g covers
// qb[0..6144) contiguously (g = m*96+seg, m*384+seg*4 = 4g). Codebook L2-hot.
__global__ __launch_bounds__(256) void vq_gather(
    const float* __restrict__ c0, const float* __restrict__ c1,
    const float* __restrict__ c2, float* __restrict__ out) {
  __shared__ int idx_s[BM];
  int lvl, blk;
  if (blockIdx.x < 512)       { lvl = 0; blk = blockIdx.x; }
  else if (blockIdx.x < 2560) { lvl = 1; blk = blockIdx.x - 512; }
  else                        { lvl = 2; blk = blockIdx.x - 2560; }
  const float* cb = (lvl == 0) ? c0 : ((lvl == 1) ? c1 : c2);
  const long ioff = (lvl == 0) ? 0 : ((lvl == 1) ? 32768 : 163840);
  const float* out_idx = out + ioff;
  float* out_q = out + ((lvl == 0) ? 294913L : ((lvl == 1) ? 12877825L : 63209473L));
  const long m0 = (long)blk * BM;

  const int tid = threadIdx.x;
  if (tid < BM) idx_s[tid] = (int)out_idx[m0 + tid];
  __syncthreads();

  float* qb = out_q + m0 * (long)D_MODEL;
#pragma unroll
  for (int u = 0; u < 24; ++u) {
    const int g = u * 256 + tid;            // 0..6143, contiguous per wave
    const int m = g / NSEG;
    const int seg = g - m * NSEG;
    *(float4*)(qb + (size_t)g * 4) = ld4(cb + (long)idx_s[m] * D_MODEL + seg * 4);
  }
}

// ---------------- deterministic loss reduce (after rescue) ----------------
__global__ __launch_bounds__(256) void loss_stage1(const float* __restrict__ dmin,
                                                   double* __restrict__ lp) {
  const int b = blockIdx.x;           // 576 blocks x 512 rows
  const int tid = threadIdx.x;
  const long r0 = (long)b * 512;
  __shared__ double sh[256];
  sh[tid] = (double)dmin[r0 + tid] + (double)dmin[r0 + 256 + tid];
  __syncthreads();
  for (int st = 128; st > 0; st >>= 1) {
    if (tid < st) sh[tid] += sh[tid + st];
    __syncthreads();
  }
  if (tid == 0) {
    double scale;
    if (b < 64)       scale = 0.05 / (32768.0 * 384.0);
    else if (b < 320) scale = 0.25 / (131072.0 * 384.0);
    else              scale = 0.60 / (131072.0 * 384.0);
    lp[b] = sh[0] * scale;
  }
}

__global__ __launch_bounds__(256) void loss_stage2(const double* __restrict__ lp,
                                                   float* __restrict__ out_loss) {
  const int tid = threadIdx.x;
  __shared__ double sh[256];
  sh[tid] = lp[tid] + lp[tid + 256] + ((tid < 64) ? lp[tid + 512] : 0.0);
  __syncthreads();
  for (int st = 128; st > 0; st >>= 1) {
    if (tid < st) sh[tid] += sh[tid + st];
    __syncthreads();
  }
  if (tid == 0) out_loss[0] = (float)sh[0];
}

extern "C" void kernel_launch(void* const* d_in, const int* in_sizes, int n_in,
                              void* d_out, int out_size, void* d_ws, size_t ws_size,
                              hipStream_t stream) {
  const float* l0 = (const float*)d_in[0];
  const float* l1 = (const float*)d_in[1];
  const float* l2 = (const float*)d_in[2];
  const float* c0 = (const float*)d_in[3];
  const float* c1 = (const float*)d_in[4];
  const float* c2 = (const float*)d_in[5];
  float* out = (float*)d_out;

  float* wsf = (float*)d_ws;
  int*   counts   = (int*)wsf;               // 4 ints
  float* en       = wsf + 4;                 // 768
  float* dmin_all = wsf + 772;               // 294912
  float* xn_all   = wsf + 295684;            // 294912
  int*   list0    = (int*)(wsf + 590596);    // cap 32768 (= all rows)
  int*   list1    = (int*)(wsf + 623364);    // cap 131072
  int*   list2    = (int*)(wsf + 754436);    // cap 131072
  double* lp      = (double*)(wsf + 885508); // 576 doubles
  half8* bh_pre   = (half8*)(wsf + 886660);  // 36864 half8 (16B-aligned)
  half8* bl_pre   = (half8*)(wsf + 1034116); // 36864 half8

  vq_norms<<<768, 64, 0, stream>>>(c0, c1, c2, en, counts);
  vq_split_cb<<<144, 256, 0, stream>>>(c0, c1, c2, bh_pre, bl_pre);

  vq_mfma_all<<<4608, 256, 0, stream>>>(l0, l1, l2, en, bh_pre, bl_pre, out,
                                        dmin_all, xn_all,
                                        list0, list1, list2, counts);

  vq_rescue_all<<<3072, 256, 0, stream>>>(l0, l1, l2, c0, c1, c2,
                                          list0, list1, list2, counts,
                                          out, dmin_all, xn_all);

  vq_gather<<<4608, 256, 0, stream>>>(c0, c1, c2, out);

  loss_stage1<<<576, 256, 0, stream>>>(dmin_all, lp);
  loss_stage2<<<1, 256, 0, stream>>>(lp, out + 294912);
}